// Round 5
// baseline (779.597 us; speedup 1.0000x reference)
//
#include <hip/hip_runtime.h>
#include <stdint.h>

#define BETA 0.9f

// ---------------------------------------------------------------------------
// Kernel 1: transpose fw1 (256, 1152) -> fw1T (1152, 256) so the fc1 spike
// row-gather is coalesced (row i = 256 contiguous floats = 1KB).
// ---------------------------------------------------------------------------
__global__ void transpose_fw1(const float* __restrict__ A, float* __restrict__ At) {
    __shared__ float tile[32][33];
    const int i0 = blockIdx.x * 32;   // i dim (1152)
    const int j0 = blockIdx.y * 32;   // j dim (256)
    const int tx = threadIdx.x, ty = threadIdx.y;
    for (int r = ty; r < 32; r += 8)
        tile[r][tx] = A[(j0 + r) * 1152 + i0 + tx];      // coalesced read over i
    __syncthreads();
    for (int r = ty; r < 32; r += 8)
        At[(i0 + r) * 256 + j0 + tx] = tile[tx][r];      // coalesced write over j
}

// ---------------------------------------------------------------------------
// Kernel 2: R21 = R16 verbatim bodies with ONE structural change:
//   reduce+LIF4(t-1) AND fc2(t-1) move onto wave 5 (idle during conv2) in
//   phase P1. s4 becomes wave-5-private (write->read same wave, lgkmcnt only,
//   no barrier). fc2 remapped to 64 lanes: 3 passes x 4 outputs, same
//   16-lane groups, same shuffle tree, same i-order -> bit-exact (R18 form).
//   Phases b4/b5 deleted: 3 barriers/step instead of 4.
// R20 lessons honored: conv2 stays fmac+win (binary form cost +26% VALU);
// conv3 stays k*64-strided (conflicts are nearly free); fc1 FROZEN.
// Race audit (all cross->=1 barrier):
//   rm1:  conv1(t+1)@P3 Or[pn] -> conv2(t+1)@P1 rd (phase-end); zero[pn]@P1(t)
//         vs Or[pn]@P3(t): b2+b3 between; last rd of pn parity was P1(t-1).
//   cm2:  conv2(t)@P1 Or[pb] -> conv3(t)@P2 rd[pb] (b2); zero[pn]@P1(t):
//         last rd @P2(t-1), next Or @P1(t+1).
//   s1e:  conv1(t+1)@P3 wr -> conv2(t+1)@P1 rd (phase-end); prev rd @P1(t)
//         before b2+b3.
//   masks: conv3(t)@P2 wr -> fc1(t)@P3 rd (b3); next wr @P2(t+1) (2 barriers).
//   pacc: fc1(t)@P3 wr -> reduce(t)@P1(t+1) rd (phase-end); next wr @P3(t+1)
//         (b2+b3 after the read).
//   s4:   wave-5 private (write and read in same wave, same phase).
// ---------------------------------------------------------------------------
__global__ __launch_bounds__(768)
__attribute__((amdgpu_waves_per_eu(6)))
void snn_main(
    const float* __restrict__ x,      // (1024, 1, 30, 100)
    const float* __restrict__ w1, const float* __restrict__ b1,
    const float* __restrict__ w2, const float* __restrict__ b2,
    const float* __restrict__ w3, const float* __restrict__ b3,
    const float* __restrict__ fw1T,   // (1152, 256) transposed
    const float* __restrict__ fb1,
    const float* __restrict__ fw2, const float* __restrict__ fb2,
    float* __restrict__ out)          // (100, 1024, 10)
{
    const int b    = blockIdx.x;
    const int tid  = threadIdx.x;
    const int e    = (tid >= 384) ? 1 : 0;   // element slot (waves 0-5 / 6-11)
    const int tl   = tid - 384 * e;          // per-element thread id (0..383)
    const int lane = tid & 63;               // hw-wave lane
    const int ew   = tl >> 6;                // per-element wave 0..5

    __shared__ float w2L[16 * 5 * 32];  // [(ci*5+k)*32 + c2]  10 KB (shared)
    __shared__ float w3L[32 * 3 * 64];  // [(ci*3+k)*64 + c3]  24 KB (shared)
    __shared__ float pacc[2][6][256];   // fc1 per-wave partials  12 KB
    __shared__ float s1e[2][16 * 24 + 8];
    __shared__ float s4[2][256];        // wave-5 private now
    __shared__ unsigned long long masks[2][18];  // s3 spikes (bit = channel)
    __shared__ unsigned int rm1[2][2][16];  // s1 row masks (bit l), t-parity
    __shared__ unsigned int cm2[2][2][20];  // s2 per-l channel masks, t-parity

    // ---- static per-thread roles (within element, 6 waves) ----
    const int c1 = tl & 15;             // conv1: channel (all 384 active)
    const int l1 = tl >> 4;             // conv1: l (0..23), exactly one each
    const int c2 = tl & 31;             // conv2: channel
    const int g2 = tl >> 5;             // conv2: l-group 0..11 (10-11 = wave 5)
    const int l02 = 2 * g2;             // pair start
    const bool c2w = (ew < 5);          // conv2 active = waves 0-4 exactly
    const unsigned wmask2 = 0x3Fu << l02;
    const int c3 = lane;                // conv3: out channel
    const int l03 = ew * 3;             // conv3: 3 positions per wave (uniform)
    // wave-5 roles: reduce j = lane + 64*q; fc2 jj = g5 + 4*pi, chf5 = lane&15
    const int g5 = lane >> 4, chf5 = lane & 15;

    // ---- stage weights into LDS (shared by both elements) ----
    for (int i = tid; i < 16 * 5 * 32; i += 768) {
        const int cc = i & 31, r = i >> 5;          // r = ci*5+k
        w2L[i] = w2[cc * 80 + r];
    }
    for (int i = tid; i < 32 * 3 * 64; i += 768) {
        const int cc = i & 63, r = i >> 6;          // r = ci*3+k
        w3L[i] = w3[cc * 96 + r];
    }
    if (tl < 16) { rm1[e][0][tl] = 0u; rm1[e][1][tl] = 0u; }
    if (tl < 20) { cm2[e][0][tl] = 0u; cm2[e][1][tl] = 0u; }
    if (tl < 8)  s1e[e][384 + tl] = 0.0f;

    // ---- per-thread register state ----
    float w1r[7];
#pragma unroll
    for (int k = 0; k < 7; ++k) w1r[k] = w1[c1 * 7 + k];
    const float b1r = b1[c1];
    const float b2r = b2[c2];
    const float b3r = b3[c3];
    // wave-5 persistent state (statically indexed, fully unrolled)
    float fb1q[4], fb2q[3];
#pragma unroll
    for (int q = 0; q < 4; ++q)
        fb1q[q] = (ew == 5) ? fb1[lane + 64 * q] : 0.0f;
#pragma unroll
    for (int pi = 0; pi < 3; ++pi) {
        const int jj = g5 + 4 * pi;
        fb2q[pi] = (ew == 5 && chf5 == 0 && jj < 10) ? fb2[jj] : 0.0f;
    }

    float m1 = 0.f;
    float m2[2] = {0.f, 0.f};
    float m3[3] = {0.f, 0.f, 0.f};
    float m4q[4] = {0.f, 0.f, 0.f, 0.f};
    float m5q[3] = {0.f, 0.f, 0.f};

    const float* xb = x + (2 * b + e) * 3000;
    const int out_b = (2 * b + e) * 10;
    const float4* fw1Tv = reinterpret_cast<const float4*>(fw1T);

    // x register load for t=0 (overlaps the staging barrier)
    float xr[7];
#pragma unroll
    for (int k = 0; k < 7; ++k) xr[k] = xb[(l1 + k) * 100];

    __syncthreads();   // staging -> compute

    // ---- peeled conv1(t=0) ----
    {
        float h = b1r;
#pragma unroll
        for (int k = 0; k < 7; ++k) h += xr[k] * w1r[k];
        float rs = (m1 > 1.0f) ? 1.0f : 0.0f;
        m1 = BETA * m1 + h - rs;
        float sa = (m1 > 1.0f) ? 1.0f : 0.0f;
        s1e[e][c1 * 24 + l1] = sa;
        if (sa != 0.0f) atomicOr(&rm1[e][0][c1], 1u << l1);
    }
    __syncthreads();   // conv1(0) -> pipeline

    for (int tau = 0; tau <= 100; ++tau) {
        const int pb = tau & 1, pn = pb ^ 1;

        // ===== P1: conv2(tau) [waves 0-4] || reduce+fc2(tau-1) [wave 5] =====
        if (tl < 16) rm1[e][pn][tl] = 0u;   // parity for step tau+1
        if (tl < 20) cm2[e][pn][tl] = 0u;
        // issue x(tau+1) loads early: consumed by conv1(tau+1) in P3
        if (tau <= 98) {
#pragma unroll
            for (int k = 0; k < 7; ++k) xr[k] = xb[(l1 + k) * 100 + tau + 1];
        }
        if (c2w) {
            if (tau <= 99) {
                // ---- conv2 + LIF2 (R16 body verbatim) ----
                float h[2] = {b2r, b2r};
#pragma unroll
                for (int ci = 0; ci < 16; ++ci) {
                    const unsigned rmv =
                        __builtin_amdgcn_readfirstlane(rm1[e][pb][ci]);
                    if ((rmv & wmask2) == 0u) continue;   // exact: 0*w skipped
                    float win[6];
#pragma unroll
                    for (int r = 0; r < 6; ++r) win[r] = s1e[e][ci * 24 + l02 + r];
                    float wk[5];
#pragma unroll
                    for (int k = 0; k < 5; ++k) wk[k] = w2L[(ci * 5 + k) * 32 + c2];
#pragma unroll
                    for (int li = 0; li < 2; ++li)
#pragma unroll
                        for (int k = 0; k < 5; ++k) h[li] += win[li + k] * wk[k];
                }
#pragma unroll
                for (int li = 0; li < 2; ++li) {
                    float rs = (m2[li] > 1.0f) ? 1.0f : 0.0f;
                    m2[li] = BETA * m2[li] + h[li] - rs;
                    if (m2[li] > 1.0f) atomicOr(&cm2[e][pb][l02 + li], 1u << c2);
                }
            }
        } else if (tau >= 1) {
            const int t45 = tau - 1;
            // ---- wave 5: fc1 reduce + LIF4 (step tau-1), R16 chain per j ----
#pragma unroll
            for (int q = 0; q < 4; ++q) {
                const int j = lane + 64 * q;
                float acc = fb1q[q];
#pragma unroll
                for (int w = 0; w < 6; ++w) acc += pacc[e][w][j];
                float rs = (m4q[q] > 1.0f) ? 1.0f : 0.0f;
                m4q[q] = BETA * m4q[q] + acc - rs;
                s4[e][j] = (m4q[q] > 1.0f) ? 1.0f : 0.0f;
            }
            // ---- wave 5: fc2 (step tau-1); s4 same-wave (lgkmcnt only) ----
            // 3 passes x 4 outputs; 16-lane groups + width-16 xor tree = the
            // exact R16 per-j chains (verified R18 form).
#pragma unroll
            for (int pi = 0; pi < 3; ++pi) {
                const int jj = g5 + 4 * pi;
                if (jj < 10) {
                    const float* wrow = fw2 + jj * 256;   // L1-hot
                    float p = 0.f;
#pragma unroll
                    for (int i = 0; i < 16; ++i)
                        p += s4[e][i * 16 + chf5] * wrow[i * 16 + chf5];
                    p += __shfl_xor(p, 8, 16);
                    p += __shfl_xor(p, 4, 16);
                    p += __shfl_xor(p, 2, 16);
                    p += __shfl_xor(p, 1, 16);
                    if (chf5 == 0) {
                        float h = fb2q[pi] + p;
                        float rs = (m5q[pi] > 1.0f) ? 1.0f : 0.0f;
                        m5q[pi] = BETA * m5q[pi] + h - rs;
                        out[t45 * 10240 + out_b + jj] =
                            (m5q[pi] > 1.0f) ? 1.0f : 0.0f;
                    }
                }
            }
        }
        __syncthreads();   // b2

        // ===== P2: conv3 + LIF3 (tau): R16 body verbatim =====
        if (tau <= 99) {
            float h[3] = {b3r, b3r, b3r};
#pragma unroll
            for (int wl = 0; wl < 5; ++wl) {   // window positions l03..l03+4
                unsigned cm = __builtin_amdgcn_readfirstlane(cm2[e][pb][l03 + wl]);
                while (cm) {               // scalar mask walk
                    const int ci = (int)__builtin_ctz(cm); cm &= cm - 1;
                    const float* wp = &w3L[ci * 192 + c3];   // + k*64
#pragma unroll
                    for (int k = 0; k < 3; ++k) {
                        const int li = wl - k;               // compile-time
                        if (li >= 0 && li < 3)
                            h[li] += wp[k * 64];             // ds_read imm offset
                    }
                }
            }
#pragma unroll
            for (int li = 0; li < 3; ++li) {
                float rs = (m3[li] > 1.0f) ? 1.0f : 0.0f;
                m3[li] = BETA * m3[li] + h[li] - rs;
                float s = (m3[li] > 1.0f) ? 1.0f : 0.0f;
                unsigned long long mk = __ballot(s != 0.0f);
                if (lane == 0) masks[e][l03 + li] = mk;
            }
        }
        __syncthreads();   // b3

        // ===== P3: conv1(tau+1) + fc1(tau): R16 bodies verbatim =====
        if (tau <= 98) {
            float h = b1r;
#pragma unroll
            for (int k = 0; k < 7; ++k) h += xr[k] * w1r[k];
            float rs = (m1 > 1.0f) ? 1.0f : 0.0f;
            m1 = BETA * m1 + h - rs;
            float sa = (m1 > 1.0f) ? 1.0f : 0.0f;
            s1e[e][c1 * 24 + l1] = sa;
            if (sa != 0.0f) atomicOr(&rm1[e][pn][c1], 1u << l1);
        }

        // ---- fc1 partials (step tau): FROZEN R16 form ----
        if (tau <= 99) {
            float4 acc4; acc4.x = acc4.y = acc4.z = acc4.w = 0.0f;
#pragma unroll 1
            for (int l = ew; l < 18; l += 6) {     // wave-uniform trip count
                const unsigned* mp = (const unsigned*)&masks[e][l];
                const unsigned mlo = __builtin_amdgcn_readfirstlane(mp[0]);
                const unsigned mhi = __builtin_amdgcn_readfirstlane(mp[1]);
                unsigned long long mk = ((unsigned long long)mhi << 32) | mlo;
                while (mk) {   // 4-wide float4 batching, whole row per wave
                    float4 f0, f1, f2, f3;
                    f0.x=f0.y=f0.z=f0.w=0.f; f1=f0; f2=f0; f3=f0;
                    int c;
                    c = (int)__builtin_ctzll(mk); mk &= mk - 1;
                    f0 = fw1Tv[(c * 18 + l) * 64 + lane];
                    if (mk) { c = (int)__builtin_ctzll(mk); mk &= mk - 1;
                              f1 = fw1Tv[(c * 18 + l) * 64 + lane]; }
                    if (mk) { c = (int)__builtin_ctzll(mk); mk &= mk - 1;
                              f2 = fw1Tv[(c * 18 + l) * 64 + lane]; }
                    if (mk) { c = (int)__builtin_ctzll(mk); mk &= mk - 1;
                              f3 = fw1Tv[(c * 18 + l) * 64 + lane]; }
                    acc4.x += f0.x; acc4.y += f0.y; acc4.z += f0.z; acc4.w += f0.w;
                    acc4.x += f1.x; acc4.y += f1.y; acc4.z += f1.z; acc4.w += f1.w;
                    acc4.x += f2.x; acc4.y += f2.y; acc4.z += f2.z; acc4.w += f2.w;
                    acc4.x += f3.x; acc4.y += f3.y; acc4.z += f3.z; acc4.w += f3.w;
                }
            }
            ((float4*)&pacc[e][ew][0])[lane] = acc4;   // partial for j=lane*4+k
        }
        __syncthreads();   // phase-end
    }
}

extern "C" void kernel_launch(void* const* d_in, const int* in_sizes, int n_in,
                              void* d_out, int out_size, void* d_ws, size_t ws_size,
                              hipStream_t stream) {
    const float* x   = (const float*)d_in[0];
    const float* w1  = (const float*)d_in[1];
    const float* b1  = (const float*)d_in[2];
    const float* w2  = (const float*)d_in[3];
    const float* b2  = (const float*)d_in[4];
    const float* w3  = (const float*)d_in[5];
    const float* b3  = (const float*)d_in[6];
    const float* fw1 = (const float*)d_in[7];
    const float* fb1 = (const float*)d_in[8];
    const float* fw2 = (const float*)d_in[9];
    const float* fb2 = (const float*)d_in[10];
    float* out  = (float*)d_out;
    float* fw1T = (float*)d_ws;   // 1152*256*4 = 1.18 MB

    dim3 tb(32, 8);
    dim3 tg(1152 / 32, 256 / 32);
    transpose_fw1<<<tg, tb, 0, stream>>>(fw1, fw1T);
    snn_main<<<512, 768, 0, stream>>>(x, w1, b1, w2, b2, w3, b3,
                                      fw1T, fb1, fw2, fb2, out);
}